// Round 8
// baseline (149.809 us; speedup 1.0000x reference)
//
#include <hip/hip_runtime.h>
#include <hip/hip_bf16.h>

// PairwiseScore: B=2, N=256, E=512, H=150 (padded to 160)
// out[b,i,j] = (m[b,i] + m[b,j] + MLP3(g_i, g_j)) / 3
//
// R8 = R7 with the compile fix (pkc was __builtin_bit_cast of __hip_bfloat162,
// not trivially copyable on this toolchain -> use hand-rolled RNE pack).
// R7 restructure: kill the per-i builder (R3-R6's latency wall) via
//   hij + hj = sum_e W1c[e,h]*(g_i[e]*g_j[e]) + hj0[h,j],  hj0 = W1b^T g_j
//  - A-operand = RAW WcF frags, staged by pure async global_load_lds DMA
//    (double-buffered 4-kt groups, 4 barriers, m97 pattern — no VALU build)
//  - B-operand = g_j frag * broadcast g_i (f32 LDS) packed in regs — no LDS
//    round-trip, no barrier
//  - hi/hj0 precomputed by tiny MFMA prep GEMM (prep_hiaj); epilogue adds
//    hjB[j][h] via coalesced L2 loads
//  - h1s stride-168 LDS exchange + phase-2 W2^T L2 ping-pong + GEMM3: R5/R6 code

typedef __attribute__((ext_vector_type(4))) float f32x4;
typedef __attribute__((ext_vector_type(4))) unsigned int u32x4;
typedef __attribute__((ext_vector_type(2))) unsigned int u32x2;
typedef __attribute__((ext_vector_type(8))) short short8;

#define NB 2
#define NN 256
#define NE 512
#define NH 150
#define HP 160      // padded H
#define NKT 16      // NE/32 k-tiles for GEMM1
#define NHT 10      // HP/16 h-tiles
#define NS 5        // HP/32 k-steps for GEMM2
#define H1S 168     // h1 LDS row stride in shorts (~2-way bank aliasing = free)
#define GRP 2560    // u32x4 rows per 4-kt stage group (4*10*64)

// ---------- helpers ----------
__device__ __forceinline__ unsigned pk_bf16(float a, float b) {
  // round-to-nearest-even bf16 pack
  unsigned ua = __builtin_bit_cast(unsigned, a);
  unsigned ub = __builtin_bit_cast(unsigned, b);
  ua += 0x7fffu + ((ua >> 16) & 1u);
  ub += 0x7fffu + ((ub >> 16) & 1u);
  return (ua >> 16) | (ub & 0xffff0000u);
}
__device__ __forceinline__ unsigned pkc(float a, float b) { return pk_bf16(a, b); }
__device__ __forceinline__ float bf_lo(unsigned u) { return __builtin_bit_cast(float, u << 16); }
__device__ __forceinline__ float bf_hi(unsigned u) { return __builtin_bit_cast(float, u & 0xffff0000u); }

__device__ __forceinline__ void async_cp16(const unsigned* gsrc, unsigned* ldst) {
  __builtin_amdgcn_global_load_lds(
      (const __attribute__((address_space(1))) unsigned*)gsrc,
      (__attribute__((address_space(3))) unsigned*)ldst, 16, 0, 0);
}

// ---------- prep: grid 466 x 256, one (row,q) per thread (unchanged R5) ----------
__global__ __launch_bounds__(256) void prep_pack(
    const float* __restrict__ g, const float* __restrict__ W1,
    const float* __restrict__ W2,
    unsigned short* __restrict__ g_bf16, unsigned short* __restrict__ WaF,
    unsigned short* __restrict__ WbF, unsigned short* __restrict__ WcF,
    unsigned short* __restrict__ W2TF)
{
  int bid = blockIdx.x, tid = threadIdx.x;
  if (bid < 256) {
    int t = bid * 256 + tid;
    f32x4 v = ((const f32x4*)g)[t];
    u32x2 o; o[0] = pk_bf16(v[0], v[1]); o[1] = pk_bf16(v[2], v[3]);
    ((u32x2*)g_bf16)[t] = o;
  } else if (bid < 416) {
    int T = (bid - 256) * 256 + tid;         // 0..40959
    int row = T >> 2, q = T & 3;             // row 0..10239 = 16kt*10ht*64lane
    int kt = row / 640; int rem = row - kt * 640;
    int l = rem & 63; int chh = rem >> 6;
    int e = kt * 32 + (l >> 4) * 8 + 2 * q;
    int h = chh * 16 + (l & 15);
    float va0 = 0.f, va1 = 0.f, vb0 = 0.f, vb1 = 0.f, vc0 = 0.f, vc1 = 0.f;
    if (h < NH) {
      va0 = W1[(size_t)e * NH + h];           va1 = W1[(size_t)(e + 1) * NH + h];
      vb0 = W1[(size_t)(512 + e) * NH + h];   vb1 = W1[(size_t)(513 + e) * NH + h];
      vc0 = W1[(size_t)(1024 + e) * NH + h];  vc1 = W1[(size_t)(1025 + e) * NH + h];
    }
    ((unsigned*)WaF)[row * 4 + q] = pk_bf16(va0, va1);
    ((unsigned*)WbF)[row * 4 + q] = pk_bf16(vb0, vb1);
    ((unsigned*)WcF)[row * 4 + q] = pk_bf16(vc0, vc1);
  } else {
    int T = (bid - 416) * 256 + tid;         // 0..12799
    int row = T >> 2, q = T & 3;             // row 0..3199 = 5s*10ht*64lane
    int s = row / 640; int rem = row - s * 640;
    int l = rem & 63; int chh = rem >> 6;
    int k = s * 32 + (l >> 4) * 8 + 2 * q;
    int hp = chh * 16 + (l & 15);
    float v0 = (k < NH && hp < NH)     ? W2[(size_t)k * NH + hp]       : 0.f;
    float v1 = (k + 1 < NH && hp < NH) ? W2[(size_t)(k + 1) * NH + hp] : 0.f;
    ((unsigned*)W2TF)[row * 4 + q] = pk_bf16(v0, v1);
  }
}

// ---------- prep2: hiA[b,n,h] = g W1a, hjB[b,n,h] = g W1b (MFMA, grid 32) ----------
__global__ __launch_bounds__(256) void prep_hiaj(
    const unsigned short* __restrict__ g_bf16, const unsigned short* __restrict__ WaF,
    const unsigned short* __restrict__ WbF,
    float* __restrict__ hiA, float* __restrict__ hjB)
{
  const int tid = threadIdx.x;
  const int b = blockIdx.x >> 4, nt = blockIdx.x & 15;
  const int lane = tid & 63, wave = tid >> 6;   // 4 waves = 2 mat x 2 htg
  const int c16 = lane & 15, quad = lane >> 4;
  const int mat = wave & 1, htg = wave >> 1;
  const unsigned short* WF = mat ? WbF : WaF;
  float* dst = mat ? hjB : hiA;

  f32x4 acc[5] = {};
  const u32x4* gB = (const u32x4*)g_bf16;
  const size_t arow = (size_t)(b * NN + nt * 16 + c16) * 64 + quad;
#pragma unroll 1
  for (int kt = 0; kt < NKT; ++kt) {
    short8 afr = __builtin_bit_cast(short8, gB[arow + (size_t)kt * 4]);  // A: g rows
#pragma unroll
    for (int ht = 0; ht < 5; ++ht) {
      short8 bfr = __builtin_bit_cast(short8,
          ((const u32x4*)WF)[(kt * NHT + htg * 5 + ht) * 64 + lane]);
      acc[ht] = __builtin_amdgcn_mfma_f32_16x16x32_bf16(afr, bfr, acc[ht], 0, 0, 0);
    }
  }
  // C: col=lane&15 = h-within-tile, row = quad*4+r = n-within-tile
#pragma unroll
  for (int ht = 0; ht < 5; ++ht) {
    int h = (htg * 5 + ht) * 16 + c16;
#pragma unroll
    for (int r = 0; r < 4; ++r) {
      int n = nt * 16 + quad * 4 + r;
      dst[(size_t)(b * NN + n) * HP + h] = acc[ht][r];
    }
  }
}

// ---------- main fused kernel: 1024 threads, one block per (b,i) ----------
__global__ __launch_bounds__(1024) void pair_main(
    const float* __restrict__ g, const float* __restrict__ mention,
    const float* __restrict__ b1, const float* __restrict__ b2,
    const float* __restrict__ W3, const float* __restrict__ b3,
    const unsigned short* __restrict__ g_bf16,
    const unsigned short* __restrict__ WcF, const unsigned short* __restrict__ W2TF,
    const float* __restrict__ hiA, const float* __restrict__ hjB,
    float* __restrict__ out)
{
  // time-shared region: phase-1 WcF stage dbuf (2x40960 B) -> h1s (86016 B)
  __shared__ alignas(16) unsigned char region[NN * H1S * 2];
  __shared__ alignas(16) float gi_f32[NE];              // g_i in f32 (2 KB)
  __shared__ alignas(16) float bias1[HP];               // hiA[i] + b1
  __shared__ alignas(16) float bias2[HP];
  __shared__ alignas(16) float w3s[HP];
  __shared__ float ps[NN];

  const int tid = threadIdx.x;
  const int bi = blockIdx.x;
  const int b = bi >> 8;
  const int lane = tid & 63, wave = tid >> 6;           // 16 waves
  const int c16 = lane & 15, quad = lane >> 4;
  const int hg = wave & 1, jg = wave >> 1;              // 2 h-groups x 8 j-groups

  unsigned* stg = (unsigned*)region;
  unsigned short* h1s = (unsigned short*)region;

  // ---- issue DMA for stage group 0 (drains at barrier A) ----
#pragma unroll
  for (int r = 0; r < 3; ++r) {
    int row = tid + r * 1024;
    if (r < 2 || tid < 512)
      async_cp16((const unsigned*)WcF + (size_t)row * 4, stg + row * 4);
  }

  // ---- phase 0: per-block constants ----
  if (tid < NE) {
    gi_f32[tid] = g[(size_t)bi * NE + tid];
  } else if (tid < NE + HP) {
    int h = tid - NE;
    bias1[h] = hiA[(size_t)bi * HP + h] + ((h < NH) ? b1[h] : 0.f);
  } else if (tid < NE + 2 * HP) {
    int h = tid - NE - HP;
    bias2[h] = (h < NH) ? b2[h] : 0.f;
  } else if (tid < NE + 3 * HP) {
    int h = tid - NE - 2 * HP;
    w3s[h] = (h < NH) ? W3[h] : 0.f;
  }
  __syncthreads();   // barrier A: DMA(0) + constants ready

  // ---- phase 1: D1[h][j] = W1c^T * (g_i o g_j); 4 DMA groups, 4 barriers ----
  f32x4 acc1[5][2] = {};
  const u32x4* gB = (const u32x4*)g_bf16;
  const size_t gidx0 = (size_t)(b * NN + jg * 32 + c16) * 64 + quad;
  const f32x4* gi4 = (const f32x4*)gi_f32;

#pragma unroll 1
  for (int grp = 0; grp < 4; ++grp) {
    if (grp < 3) {      // fire-and-forget DMA for group grp+1 into other half
#pragma unroll
      for (int r = 0; r < 3; ++r) {
        int row = tid + r * 1024;
        if (r < 2 || tid < 512)
          async_cp16((const unsigned*)WcF + ((size_t)(grp + 1) * GRP + row) * 4,
                     stg + (((grp + 1) & 1) * GRP + row) * 4);
      }
    }
    const u32x4* As = (const u32x4*)stg + (grp & 1) * GRP;
#pragma unroll
    for (int ktl = 0; ktl < 4; ++ktl) {
      int kt = grp * 4 + ktl;
      u32x4 g0r = gB[gidx0 + (size_t)kt * 4];            // g_j rows, jt0
      u32x4 g1r = gB[gidx0 + 16 * 64 + (size_t)kt * 4];  // jt1
      f32x4 ga = gi4[kt * 8 + quad * 2];                 // broadcast g_i octet
      f32x4 gc = gi4[kt * 8 + quad * 2 + 1];
      u32x4 p0, p1;
      p0[0] = pkc(bf_lo(g0r[0]) * ga[0], bf_hi(g0r[0]) * ga[1]);
      p0[1] = pkc(bf_lo(g0r[1]) * ga[2], bf_hi(g0r[1]) * ga[3]);
      p0[2] = pkc(bf_lo(g0r[2]) * gc[0], bf_hi(g0r[2]) * gc[1]);
      p0[3] = pkc(bf_lo(g0r[3]) * gc[2], bf_hi(g0r[3]) * gc[3]);
      p1[0] = pkc(bf_lo(g1r[0]) * ga[0], bf_hi(g1r[0]) * ga[1]);
      p1[1] = pkc(bf_lo(g1r[1]) * ga[2], bf_hi(g1r[1]) * ga[3]);
      p1[2] = pkc(bf_lo(g1r[2]) * gc[0], bf_hi(g1r[2]) * gc[1]);
      p1[3] = pkc(bf_lo(g1r[3]) * gc[2], bf_hi(g1r[3]) * gc[3]);
      short8 bf0 = __builtin_bit_cast(short8, p0);
      short8 bf1 = __builtin_bit_cast(short8, p1);
#pragma unroll
      for (int ht = 0; ht < 5; ++ht) {
        short8 af = __builtin_bit_cast(short8, As[(ktl * NHT + hg * 5 + ht) * 64 + lane]);
        acc1[ht][0] = __builtin_amdgcn_mfma_f32_16x16x32_bf16(af, bf0, acc1[ht][0], 0, 0, 0);
        acc1[ht][1] = __builtin_amdgcn_mfma_f32_16x16x32_bf16(af, bf1, acc1[ht][1], 0, 0, 0);
      }
    }
    __syncthreads();  // group grp reads done; DMA(grp+1) drained
  }

  // ---- epilogue 1: h1 = relu(D1 + hiA[i] + b1 + hjB[j]) -> bf16 LDS [j][h] ----
#pragma unroll
  for (int ht = 0; ht < 5; ++ht) {
    const int HT = hg * 5 + ht;
    f32x4 bv = *(const f32x4*)(bias1 + HT * 16 + quad * 4);
#pragma unroll
    for (int jt = 0; jt < 2; ++jt) {
      int j = jg * 32 + jt * 16 + c16;
      f32x4 hv = *(const f32x4*)(hjB + (size_t)(b * NN + j) * HP + HT * 16 + quad * 4);
      f32x4 v = acc1[ht][jt];
      float r0 = fmaxf(v[0] + bv[0] + hv[0], 0.f);
      float r1 = fmaxf(v[1] + bv[1] + hv[1], 0.f);
      float r2 = fmaxf(v[2] + bv[2] + hv[2], 0.f);
      float r3 = fmaxf(v[3] + bv[3] + hv[3], 0.f);
      u32x2 pr; pr[0] = pkc(r0, r1); pr[1] = pkc(r2, r3);
      *(u32x2*)(h1s + j * H1S + HT * 16 + quad * 4) = pr;
    }
  }
  __syncthreads();   // barrier F: h1 complete (cross-hg exchange)

  // ---- phase 2: D2[h'][j] = W2^T * h1 ; A from L2 ping-pong, B from LDS ----
  f32x4 acc2[5][2] = {};
  u32x4 wf[2][5];
#pragma unroll
  for (int ht = 0; ht < 5; ++ht)
    wf[0][ht] = ((const u32x4*)W2TF)[(hg * 5 + ht) * 64 + lane];

#pragma unroll
  for (int s = 0; s < NS; ++s) {
    if (s + 1 < NS) {
#pragma unroll
      for (int ht = 0; ht < 5; ++ht)
        wf[(s + 1) & 1][ht] =
            ((const u32x4*)W2TF)[((s + 1) * NHT + hg * 5 + ht) * 64 + lane];
    }
    short8 b2f[2];
#pragma unroll
    for (int jt = 0; jt < 2; ++jt) {
      int j = jg * 32 + jt * 16 + c16;
      b2f[jt] = *(const short8*)(h1s + j * H1S + s * 32 + quad * 8);
    }
#pragma unroll
    for (int ht = 0; ht < 5; ++ht) {
      short8 af = __builtin_bit_cast(short8, wf[s & 1][ht]);
      acc2[ht][0] = __builtin_amdgcn_mfma_f32_16x16x32_bf16(af, b2f[0], acc2[ht][0], 0, 0, 0);
      acc2[ht][1] = __builtin_amdgcn_mfma_f32_16x16x32_bf16(af, b2f[1], acc2[ht][1], 0, 0, 0);
    }
  }

  // ---- epilogue 2 + GEMM3: partial score over own h' range ----
  float part0 = 0.f, part1 = 0.f;
#pragma unroll
  for (int ht = 0; ht < 5; ++ht) {
    const int HT = hg * 5 + ht;
    f32x4 bv = *(const f32x4*)(bias2 + HT * 16 + quad * 4);
    f32x4 wv = *(const f32x4*)(w3s + HT * 16 + quad * 4);
    f32x4 v0 = acc2[ht][0], v1 = acc2[ht][1];
#pragma unroll
    for (int r = 0; r < 4; ++r) {
      part0 += fmaxf(v0[r] + bv[r], 0.f) * wv[r];
      part1 += fmaxf(v1[r] + bv[r], 0.f) * wv[r];
    }
  }
  part0 += __shfl_xor(part0, 16); part0 += __shfl_xor(part0, 32);
  part1 += __shfl_xor(part1, 16); part1 += __shfl_xor(part1, 32);

  // ---- cross-hg combine via LDS, hg1 writes out ----
  if (hg == 0) {
    if (quad == 0) ps[jg * 32 + c16] = part0;
    if (quad == 1) ps[jg * 32 + 16 + c16] = part1;
  }
  __syncthreads();   // barrier G

  if (hg == 1 && quad < 2) {
    int j = jg * 32 + quad * 16 + c16;
    float sc = (quad == 0) ? part0 : part1;
    int i = bi & 255;
    float mi = mention[b * NN + i];
    float mj = mention[b * NN + j];
    out[(size_t)bi * NN + j] = (mi + mj + ps[j] + sc + b3[0]) * (1.f / 3.f);
  }
}

// ---------- launch ----------
extern "C" void kernel_launch(void* const* d_in, const int* in_sizes, int n_in,
                              void* d_out, int out_size, void* d_ws, size_t ws_size,
                              hipStream_t stream) {
  const float* g  = (const float*)d_in[0];
  const float* m  = (const float*)d_in[1];
  const float* W1 = (const float*)d_in[2];
  const float* b1 = (const float*)d_in[3];
  const float* W2 = (const float*)d_in[4];
  const float* b2 = (const float*)d_in[5];
  const float* W3 = (const float*)d_in[6];
  const float* b3 = (const float*)d_in[7];
  float* out = (float*)d_out;

  char* ws = (char*)d_ws;
  unsigned short* g_bf16 = (unsigned short*)(ws);              //  524288 B
  unsigned short* WaF    = (unsigned short*)(ws + 524288);     //  163840 B
  unsigned short* WbF    = (unsigned short*)(ws + 688128);     //  163840 B
  unsigned short* WcF    = (unsigned short*)(ws + 851968);     //  163840 B
  unsigned short* W2TF   = (unsigned short*)(ws + 1015808);    //   51200 B
  float*          hiA    = (float*)(ws + 1067008);             //  327680 B
  float*          hjB    = (float*)(ws + 1394688);             //  327680 B (~1.72 MB)

  prep_pack<<<466, 256, 0, stream>>>(g, W1, W2, g_bf16, WaF, WbF, WcF, W2TF);
  prep_hiaj<<<32, 256, 0, stream>>>(g_bf16, WaF, WbF, hiA, hjB);
  pair_main<<<512, 1024, 0, stream>>>(g, m, b1, b2, W3, b3, g_bf16, WcF, W2TF,
                                      hiA, hjB, out);
}